// Round 1
// baseline (1949.415 us; speedup 1.0000x reference)
//
#include <hip/hip_runtime.h>
#include <hip/hip_bf16.h>

// GC-LSTM fused kernel. B=16, T=128, N=256, F=H=128.
// z-col order (i,f,o,c): Wx = [Wix|Wfx|Wox|Wcx], Wm = [Wim|Wfm|Wom|Wcm]
// out[((t*B+b)*N+n)*H+h] = h_t  (raw reshape of [T,B,N,H])

typedef __bf16 bf16x8 __attribute__((ext_vector_type(8)));
typedef float f32x4 __attribute__((ext_vector_type(4)));

__device__ __forceinline__ unsigned short f2bf(float f) {
  unsigned int u = __float_as_uint(f);
  u += 0x7FFFu + ((u >> 16) & 1u);   // RNE
  return (unsigned short)(u >> 16);
}
__device__ __forceinline__ float sigm(float v) {
  return __fdividef(1.f, 1.f + __expf(-v));
}
__device__ __forceinline__ float tanh_(float v) {
  return 2.f * __fdividef(1.f, 1.f + __expf(-2.f * v)) - 1.f;
}

// Pack weights transposed to bf16: WxT[g][f] (g in [0,512) order i,f,o,c), WmT likewise.
// Also zero h0 (bf16 [4096][128]) and c0 (f32 [4096][128]) — ws is re-poisoned each call.
__global__ __launch_bounds__(256) void setup_k(
    const float* __restrict__ Wix, const float* __restrict__ Wfx,
    const float* __restrict__ Wox, const float* __restrict__ Wcx,
    const float* __restrict__ Wim, const float* __restrict__ Wfm,
    const float* __restrict__ Wom, const float* __restrict__ Wcm,
    unsigned short* __restrict__ WxT, unsigned short* __restrict__ WmT,
    unsigned short* __restrict__ h0, float* __restrict__ c0) {
  int i = blockIdx.x * 256 + threadIdx.x;  // grid covers 524288
  if (i < 65536) {
    int g = i >> 7, f = i & 127;
    int gi = g & 127;
    const float* sx = (g < 128) ? Wix : (g < 256) ? Wfx : (g < 384) ? Wox : Wcx;
    const float* sm = (g < 128) ? Wim : (g < 256) ? Wfm : (g < 384) ? Wom : Wcm;
    WxT[i] = f2bf(sx[f * 128 + gi]);
    WmT[i] = f2bf(sm[f * 128 + gi]);
  }
  if (i < 524288) { h0[i] = 0; c0[i] = 0.f; }
}

// One time step. z = h_in @ Wm + x_t @ Wx + bias ; gates ; writes h_out (bf16),
// c (f32, in-place), out slice (f32).
// Grid: (64 row-blocks of 64 rows) x (4 hcol groups of 32). 256 threads = 4 waves.
// Wave w owns rows rb*64+w*16 .. +16. MFMA 16x16x32 bf16, K=256 in 8 chunks.
__global__ __launch_bounds__(256) void lstm_step(
    const float* __restrict__ x,
    const unsigned short* __restrict__ WxT,
    const unsigned short* __restrict__ WmT,
    const unsigned short* __restrict__ h_in,
    unsigned short* __restrict__ h_out,
    float* __restrict__ c_st,
    const float* __restrict__ b_i, const float* __restrict__ b_f,
    const float* __restrict__ b_o, const float* __restrict__ b_c,
    float* __restrict__ out, int t) {
  const int w = threadIdx.x >> 6, l = threadIdx.x & 63;
  const int lr = l & 15, lh = l >> 4;
  const int rb = blockIdx.x;   // 0..63
  const int gq = blockIdx.y;   // 0..3
  const int r0 = rb * 64 + w * 16;

  // ---- A fragments: lane holds row (r0+lr), k-chunk lh*8..+8 of each 32-block
  const int arow = r0 + lr;
  bf16x8 ah[4], ax[4];
  {
    const unsigned short* hp = h_in + (size_t)arow * 128 + lh * 8;
#pragma unroll
    for (int kk = 0; kk < 4; ++kk) ah[kk] = *(const bf16x8*)(hp + kk * 32);
    const int bb = arow >> 8, nn = arow & 255;
    // x[b][t][n][f], f-major
    const float* xp = x + ((size_t)(bb * 128 + t) * 256 + nn) * 128 + lh * 8;
#pragma unroll
    for (int kk = 0; kk < 4; ++kk) {
      float4 f0 = *(const float4*)(xp + kk * 32);
      float4 f1 = *(const float4*)(xp + kk * 32 + 4);
      union { unsigned short us[8]; bf16x8 v; } cv;
      cv.us[0] = f2bf(f0.x); cv.us[1] = f2bf(f0.y);
      cv.us[2] = f2bf(f0.z); cv.us[3] = f2bf(f0.w);
      cv.us[4] = f2bf(f1.x); cv.us[5] = f2bf(f1.y);
      cv.us[6] = f2bf(f1.z); cv.us[7] = f2bf(f1.w);
      ax[kk] = cv.v;
    }
  }

  // ---- GEMM: acc[gate][q] covers z cols gate*128 + gq*32 + q*16 .. +16
  f32x4 acc[4][2];
#pragma unroll
  for (int g = 0; g < 4; ++g) {
#pragma unroll
    for (int q = 0; q < 2; ++q) {
      const int ni = g * 8 + gq * 2 + q;   // col fragment index (of 32)
      const unsigned short* bm = WmT + (size_t)(ni * 16 + lr) * 128 + lh * 8;
      const unsigned short* bx = WxT + (size_t)(ni * 16 + lr) * 128 + lh * 8;
      f32x4 a_ = {0.f, 0.f, 0.f, 0.f};
#pragma unroll
      for (int kk = 0; kk < 4; ++kk)
        a_ = __builtin_amdgcn_mfma_f32_16x16x32_bf16(
            ah[kk], *(const bf16x8*)(bm + kk * 32), a_, 0, 0, 0);
#pragma unroll
      for (int kk = 0; kk < 4; ++kk)
        a_ = __builtin_amdgcn_mfma_f32_16x16x32_bf16(
            ax[kk], *(const bf16x8*)(bx + kk * 32), a_, 0, 0, 0);
      acc[g][q] = a_;
    }
  }

  // ---- Gates + state update. C/D layout: row = lh*4 + r, col = lr (m89-verified).
#pragma unroll
  for (int q = 0; q < 2; ++q) {
    const int hcol = gq * 32 + q * 16 + lr;
    const float biv = b_i[hcol], bfv = b_f[hcol], bov = b_o[hcol], bcv = b_c[hcol];
#pragma unroll
    for (int r = 0; r < 4; ++r) {
      const int row = r0 + lh * 4 + r;
      const float zi = acc[0][q][r] + biv;
      const float zf = acc[1][q][r] + bfv;
      const float zo = acc[2][q][r] + bov;
      const float zc = acc[3][q][r] + bcv;
      const float iv = sigm(zi), fv = sigm(zf), ov = sigm(zo), gv = tanh_(zc);
      const size_t ci = (size_t)row * 128 + hcol;
      const float cn = fv * c_st[ci] + iv * gv;
      c_st[ci] = cn;
      const float hv = ov * tanh_(cn);
      h_out[ci] = f2bf(hv);
      const int bb = row >> 8, nn = row & 255;
      out[((size_t)(t * 16 + bb) * 256 + nn) * 128 + hcol] = hv;
    }
  }
}

extern "C" void kernel_launch(void* const* d_in, const int* in_sizes, int n_in,
                              void* d_out, int out_size, void* d_ws, size_t ws_size,
                              hipStream_t stream) {
  (void)in_sizes; (void)n_in; (void)out_size; (void)ws_size;
  // setup_inputs order: 0:x 1:Wix 2:Wim 3:Wfx 4:Wfm 5:Wcx 6:Wcm 7:Wox 8:Wom
  //                     9:bi 10:bf 11:bc 12:bo
  const float* x   = (const float*)d_in[0];
  const float* Wix = (const float*)d_in[1];
  const float* Wim = (const float*)d_in[2];
  const float* Wfx = (const float*)d_in[3];
  const float* Wfm = (const float*)d_in[4];
  const float* Wcx = (const float*)d_in[5];
  const float* Wcm = (const float*)d_in[6];
  const float* Wox = (const float*)d_in[7];
  const float* Wom = (const float*)d_in[8];
  const float* bi  = (const float*)d_in[9];
  const float* bf  = (const float*)d_in[10];
  const float* bc  = (const float*)d_in[11];
  const float* bo  = (const float*)d_in[12];

  char* ws = (char*)d_ws;
  unsigned short* WxT = (unsigned short*)(ws);             // 128 KB
  unsigned short* WmT = (unsigned short*)(ws + 131072);    // 128 KB
  unsigned short* hA  = (unsigned short*)(ws + 262144);    // 1 MB  bf16 [4096][128]
  unsigned short* hB  = (unsigned short*)(ws + 1310720);   // 1 MB
  float*          cS  = (float*)(ws + 2359296);            // 2 MB  f32 [4096][128]
  float* out = (float*)d_out;

  setup_k<<<2048, 256, 0, stream>>>(Wix, Wfx, Wox, Wcx, Wim, Wfm, Wom, Wcm,
                                    WxT, WmT, hA, cS);

  unsigned short* hin = hA;
  unsigned short* hout = hB;
  for (int t = 0; t < 128; ++t) {
    lstm_step<<<dim3(64, 4), 256, 0, stream>>>(x, WxT, WmT, hin, hout, cS,
                                               bi, bf, bo, bc, out, t);
    unsigned short* tmp = hin; hin = hout; hout = tmp;
  }
}

// Round 3
// 640.797 us; speedup vs baseline: 3.0422x; 3.0422x over previous
//
#include <hip/hip_runtime.h>
#include <hip/hip_bf16.h>

// GC-LSTM persistent kernel. B=16, T=128, N=256, F=H=128.
// Rows (b,n) are independent through the recurrence -> each block owns 16 rows
// and loops over all 128 timesteps internally. One launch, no grid sync.
// z-col order (i,f,o,c). out[((t*16+b)*256+n)*128+h] = h_t (raw [T,B,N,H] reshape).

typedef __bf16 bf16x8 __attribute__((ext_vector_type(8)));
typedef float f32x4 __attribute__((ext_vector_type(4)));

#define PITCH 136  // LDS row pitch in bf16 elems (128 + 8 pad -> 272B rows, 2-way max aliasing)

__device__ __forceinline__ unsigned short f2bf(float f) {
  unsigned int u = __float_as_uint(f);
  u += 0x7FFFu + ((u >> 16) & 1u);  // RNE
  return (unsigned short)(u >> 16);
}
__device__ __forceinline__ unsigned long long pack4(float4 v) {
  return (unsigned long long)f2bf(v.x) |
         ((unsigned long long)f2bf(v.y) << 16) |
         ((unsigned long long)f2bf(v.z) << 32) |
         ((unsigned long long)f2bf(v.w) << 48);
}
__device__ __forceinline__ float sigm(float v) {
  return __fdividef(1.f, 1.f + __expf(-v));
}
__device__ __forceinline__ float tanh_(float v) {
  return 2.f * __fdividef(1.f, 1.f + __expf(-2.f * v)) - 1.f;
}

// Pack combined transposed weights: WT[zc][k], zc = g*128+hc (g: i,f,o,c),
// k<128 -> Wm_g[k][hc], k>=128 -> Wx_g[k-128][hc]. bf16. [512][256] = 256 KB.
__global__ __launch_bounds__(256) void pack_w(
    const float* __restrict__ Wim, const float* __restrict__ Wfm,
    const float* __restrict__ Wom, const float* __restrict__ Wcm,
    const float* __restrict__ Wix, const float* __restrict__ Wfx,
    const float* __restrict__ Wox, const float* __restrict__ Wcx,
    unsigned short* __restrict__ WT) {
  int i = blockIdx.x * 256 + threadIdx.x;  // < 131072
  int zc = i >> 8, k = i & 255;
  int g = zc >> 7, hcol = zc & 127;
  const float* Wm_ = (g == 0) ? Wim : (g == 1) ? Wfm : (g == 2) ? Wom : Wcm;
  const float* Wx_ = (g == 0) ? Wix : (g == 1) ? Wfx : (g == 2) ? Wox : Wcx;
  float v = (k < 128) ? Wm_[k * 128 + hcol] : Wx_[(k - 128) * 128 + hcol];
  WT[i] = f2bf(v);
}

// Persistent LSTM. Grid 256 blocks x 512 threads (8 waves).
// Block owns rows r0..r0+16 (same batch b). Wave w owns hcols [16w,16w+16)
// for all 4 gates (z-col frags ni = g*8+w). 32 MFMA 16x16x32 bf16 per wave/step.
// Weights in VGPRs (loaded once). c in registers. h double-buffered in LDS.
__global__ __launch_bounds__(512, 2) void lstm_persist(
    const float* __restrict__ x,
    const unsigned short* __restrict__ WT,
    const float* __restrict__ b_i, const float* __restrict__ b_f,
    const float* __restrict__ b_o, const float* __restrict__ b_c,
    float* __restrict__ out) {
  __shared__ unsigned short hbuf[2][16 * PITCH];
  __shared__ unsigned short xbuf[2][16 * PITCH];

  const int tid = threadIdx.x;
  const int w = tid >> 6, l = tid & 63;
  const int lr = l & 15, lh = l >> 4;
  const int bb = blockIdx.x >> 4;          // batch index 0..15
  const int n0 = (blockIdx.x & 15) << 4;   // node start (16 nodes per block)
  const int hc = (w << 4) + lr;            // this lane's h-column

  // ---- B fragments -> registers, resident for the whole kernel.
  // B[g][kk]: lane holds W[k = kk*32 + lh*8 + j][zcol = (g*8+w)*16 + lr], j=0..7
  bf16x8 B[4][8];
#pragma unroll
  for (int g = 0; g < 4; ++g)
#pragma unroll
    for (int kk = 0; kk < 8; ++kk)
      B[g][kk] = *(const bf16x8*)(WT +
          (size_t)(((g * 8 + w) * 16 + lr)) * 256 + lh * 8 + kk * 32);

  const float biv = b_i[hc], bfv = b_f[hc], bov = b_o[hc], bcv = b_c[hc];

  // ---- init: hbuf[0] = 0, xbuf[0] = bf16(x[t=0] slice)
  const int xrow = tid >> 5, xcol = (tid & 31) << 2;  // covers [16][128] via 4 elems/thread
  *(unsigned long long*)(&hbuf[0][xrow * PITCH + xcol]) = 0ull;
  const float* xblk = x + ((size_t)bb * 128 * 256 + n0) * 128;  // + t*256*128
  {
    float4 x0 = *(const float4*)(xblk + tid * 4);
    *(unsigned long long*)(&xbuf[0][xrow * PITCH + xcol]) = pack4(x0);
  }
  float cr[4] = {0.f, 0.f, 0.f, 0.f};  // cell state, r = 0..3 (static idx only)
  __syncthreads();

  for (int t = 0; t < 128; ++t) {
    const int cur = t & 1, nxt = cur ^ 1;

    // prefetch x[t+1] (clamped; latency hidden under MFMA+gates)
    const int tp = (t + 1 < 128) ? t + 1 : 127;
    float4 xp = *(const float4*)(xblk + (size_t)tp * 32768 + tid * 4);

    // A fragments: lane holds row lr, k = kk*32 + lh*8 + j
    bf16x8 ah[4], ax[4];
#pragma unroll
    for (int kk = 0; kk < 4; ++kk) {
      ah[kk] = *(const bf16x8*)(&hbuf[cur][lr * PITCH + lh * 8 + kk * 32]);
      ax[kk] = *(const bf16x8*)(&xbuf[cur][lr * PITCH + lh * 8 + kk * 32]);
    }

    f32x4 acc[4];
#pragma unroll
    for (int g = 0; g < 4; ++g) {
      f32x4 a_ = {0.f, 0.f, 0.f, 0.f};
#pragma unroll
      for (int kk = 0; kk < 4; ++kk)
        a_ = __builtin_amdgcn_mfma_f32_16x16x32_bf16(ah[kk], B[g][kk], a_, 0, 0, 0);
#pragma unroll
      for (int kk = 0; kk < 4; ++kk)
        a_ = __builtin_amdgcn_mfma_f32_16x16x32_bf16(ax[kk], B[g][kk + 4], a_, 0, 0, 0);
      acc[g] = a_;
    }

    // gates + state update. C/D layout: row = lh*4 + r, col = lr (hcol = hc).
    float* outt = out + ((size_t)(t * 16 + bb) * 256 + n0) * 128;
#pragma unroll
    for (int r = 0; r < 4; ++r) {
      const float iv = sigm(acc[0][r] + biv);
      const float fv = sigm(acc[1][r] + bfv);
      const float ov = sigm(acc[2][r] + bov);
      const float gv = tanh_(acc[3][r] + bcv);
      const float cn = fv * cr[r] + iv * gv;
      cr[r] = cn;
      const float hv = ov * tanh_(cn);
      const int row = lh * 4 + r;
      outt[row * 128 + hc] = hv;
      hbuf[nxt][row * PITCH + hc] = f2bf(hv);
    }

    // x[t+1] -> LDS (after compute; vmcnt wait inserted by compiler)
    *(unsigned long long*)(&xbuf[nxt][xrow * PITCH + xcol]) = pack4(xp);

    __syncthreads();
  }
}

extern "C" void kernel_launch(void* const* d_in, const int* in_sizes, int n_in,
                              void* d_out, int out_size, void* d_ws, size_t ws_size,
                              hipStream_t stream) {
  (void)in_sizes; (void)n_in; (void)out_size; (void)ws_size;
  // setup_inputs order: 0:x 1:Wix 2:Wim 3:Wfx 4:Wfm 5:Wcx 6:Wcm 7:Wox 8:Wom
  //                     9:bi 10:bf 11:bc 12:bo   (note: bc before bo)
  const float* x   = (const float*)d_in[0];
  const float* Wix = (const float*)d_in[1];
  const float* Wim = (const float*)d_in[2];
  const float* Wfx = (const float*)d_in[3];
  const float* Wfm = (const float*)d_in[4];
  const float* Wcx = (const float*)d_in[5];
  const float* Wcm = (const float*)d_in[6];
  const float* Wox = (const float*)d_in[7];
  const float* Wom = (const float*)d_in[8];
  const float* bi  = (const float*)d_in[9];
  const float* bf  = (const float*)d_in[10];
  const float* bc  = (const float*)d_in[11];
  const float* bo  = (const float*)d_in[12];

  unsigned short* WT = (unsigned short*)d_ws;  // 256 KB packed weights
  float* out = (float*)d_out;

  pack_w<<<512, 256, 0, stream>>>(Wim, Wfm, Wom, Wcm, Wix, Wfx, Wox, Wcx, WT);
  lstm_persist<<<256, 512, 0, stream>>>(x, WT, bi, bf, bo, bc, out);
}